// Round 6
// baseline (99.994 us; speedup 1.0000x reference)
//
#include <hip/hip_runtime.h>
#include <hip/hip_bf16.h>
#include <stdint.h>

// CapsNet routing, size-1 softmax axis => cj==1 => one GEMM + squash:
//   s[b][c] = sum_t In[b][t] * W2[t][c]   b<64, t<16384 (=i*8+k), c<512 (=j*16+l)
//   W2[t][c] addr in W[I][J][K][L]: i*4096 + j*128 + k*16 + l
// Verified (rounds 3/4 PASS) mfma_f32_16x16x32_bf16 layouts:
//   A[row][k]: row=lane&15, k=(lane>>4)*8+e ; B same k mapping, col=lane&15
//   D[row][col]: col=lane&15, row=(lane>>4)*4+reg
// fp32 accuracy via hi/lo bf16 split (hh + lh + hl).
// Round-5/6: (1) gemm atomically accumulates into a 128KB acc in ws
// (kills the 16+16MB partial round-trip and the latency-bound finish);
// (2) In pre-converted once to bf16 hi/lo (prep kernel) -> A-frags are raw
// 16B loads, no per-step cvt; (3) 512 blocks, no LDS, no barriers.

using f32x4 = __attribute__((ext_vector_type(4))) float;
using s16x4 = __attribute__((ext_vector_type(4))) short;
using s16x8 = __attribute__((ext_vector_type(8))) short;

__device__ __forceinline__ short f2bf(float x) {
    __hip_bfloat16 h = __float2bfloat16(x);   // RNE
    return *reinterpret_cast<short*>(&h);
}
__device__ __forceinline__ float bf2f(short s) {
    return __uint_as_float(((uint32_t)(uint16_t)s) << 16);
}

// ws layout: [0, 32768) fp32 accumulator (zeroed by prep);
//            then In_hi[1M] shorts, In_lo[1M] shorts (4 MB total).

__global__ __launch_bounds__(256)
void caps_prep(const float* __restrict__ In, float* __restrict__ ws)
{
    const int g = blockIdx.x * 256 + threadIdx.x;   // 1024 blocks -> 262144
    short* hi = (short*)(ws + 32768);
    short* lo = hi + (1 << 20);
    f32x4 v = *(const f32x4*)(In + (size_t)g * 4);
    s16x4 h4, l4;
    #pragma unroll
    for (int e = 0; e < 4; ++e) {
        short h = f2bf(v[e]);
        h4[e] = h;
        l4[e] = f2bf(v[e] - bf2f(h));
    }
    *(s16x4*)(hi + (size_t)g * 4) = h4;
    *(s16x4*)(lo + (size_t)g * 4) = l4;
    if (blockIdx.x < 128) ws[blockIdx.x * 256 + threadIdx.x] = 0.0f;  // zero acc
}

struct WReg { float v[8]; };                 // W2[kb+q*8+e][j*16+cin]
struct AReg { s16x8 h[4], l[4]; };           // In bf16 frags per mt

__global__ __launch_bounds__(256)
void caps_gemm_at(const float* __restrict__ W, float* __restrict__ ws)
{
    const int tid = threadIdx.x, wv = tid >> 6, lane = tid & 63;
    const int q = lane >> 4, cin = lane & 15;
    const int kb0 = blockIdx.x * 256;        // 64 k-splits of 256 t
    const int j   = blockIdx.y * 4 + wv;     // wave owns c-range [j*16, j*16+16)
    const short* hi = (const short*)(ws + 32768);
    const short* lo = hi + (1 << 20);
    const float* wbase = W + (size_t)j * 128 + cin;

    f32x4 acc[4] = {};                       // [mt], D = 16b x 16c per mt

    auto load_step = [&](int s, WReg& wr, AReg& ar) {
        const int i0 = (kb0 >> 3) + s * 4 + q;          // t-run q*8 is 8-aligned
        const float* wp = wbase + (size_t)i0 * 4096;
        #pragma unroll
        for (int e = 0; e < 8; ++e) wr.v[e] = wp[e * 16];   // k=e, 64B lines full
        const int kb = kb0 + s * 32 + q * 8;
        #pragma unroll
        for (int mt = 0; mt < 4; ++mt) {
            const size_t o = (size_t)(mt * 16 + cin) * 16384 + kb;
            ar.h[mt] = *(const s16x8*)(hi + o);         // these ARE the A-frags
            ar.l[mt] = *(const s16x8*)(lo + o);
        }
    };

    auto compute = [&](const WReg& wr, const AReg& ar) {
        s16x8 Bh, Bl;
        #pragma unroll
        for (int e = 0; e < 8; ++e) {
            short h = f2bf(wr.v[e]);
            Bh[e] = h;
            Bl[e] = f2bf(wr.v[e] - bf2f(h));
        }
        #pragma unroll
        for (int mt = 0; mt < 4; ++mt) {
            acc[mt] = __builtin_amdgcn_mfma_f32_16x16x32_bf16(ar.h[mt], Bh, acc[mt], 0, 0, 0);
            acc[mt] = __builtin_amdgcn_mfma_f32_16x16x32_bf16(ar.l[mt], Bh, acc[mt], 0, 0, 0);
            acc[mt] = __builtin_amdgcn_mfma_f32_16x16x32_bf16(ar.h[mt], Bl, acc[mt], 0, 0, 0);
        }
    };

    WReg wA, wB; AReg aA, aB;                // statically-named double buffer
    load_step(0, wA, aA);
    #pragma unroll 1
    for (int ss = 0; ss < 8; ss += 2) {
        load_step(ss + 1, wB, aB);
        compute(wA, aA);
        if (ss + 2 < 8) load_step(ss + 2, wA, aA);
        compute(wB, aB);
    }

    // D: row b = mt*16 + q*4 + r, col c = j*16 + cin
    #pragma unroll
    for (int mt = 0; mt < 4; ++mt) {
        const int b = mt * 16 + q * 4;
        #pragma unroll
        for (int r = 0; r < 4; ++r)
            atomicAdd(ws + (b + r) * 512 + j * 16 + cin, acc[mt][r]);
    }
}

__global__ __launch_bounds__(256)
void caps_squash(const float* __restrict__ ws, float* __restrict__ out)
{
    const int o = blockIdx.x * 256 + threadIdx.x;   // o = b*512 + j*16 + l
    float s = ws[o];
    float s2 = s * s;                               // sum over l (16 lanes)
    s2 += __shfl_xor(s2, 1);
    s2 += __shfl_xor(s2, 2);
    s2 += __shfl_xor(s2, 4);
    s2 += __shfl_xor(s2, 8);
    const float scale = s2 / (1.0f + s2);
    out[o] = s * scale / sqrtf(s2 + 1e-7f);
}

// ---------- fallback (ws too small; practically never taken) ----------
__global__ __launch_bounds__(256)
void caps_gemm_direct(const float* __restrict__ In, const float* __restrict__ W,
                      float* __restrict__ outp)
{
    const int tid = threadIdx.x, wv = tid >> 6, lane = tid & 63;
    const int q = lane >> 4, cin = lane & 15;
    const int c0 = blockIdx.y * 128 + wv * 32;
    f32x4 acc[4][2] = {};
    #pragma unroll 1
    for (int ssk = 0; ssk < 512; ++ssk) {
        const int kb = ssk * 32;
        const int i0 = (kb >> 3) + q;
        float wvv[2][8];
        s16x8 Ah[4], Al[4];
        #pragma unroll
        for (int nt = 0; nt < 2; ++nt) {
            const int c = c0 + nt * 16 + cin;
            const float* wp = W + (size_t)i0 * 4096 + (c >> 4) * 128 + (c & 15);
            #pragma unroll
            for (int e = 0; e < 8; ++e) wvv[nt][e] = wp[e * 16];
        }
        #pragma unroll
        for (int mt = 0; mt < 4; ++mt) {
            const float* ip = In + (size_t)(mt * 16 + cin) * 16384 + kb + q * 8;
            #pragma unroll
            for (int e = 0; e < 8; ++e) {
                float x = ip[e];
                short h = f2bf(x);
                Ah[mt][e] = h;
                Al[mt][e] = f2bf(x - bf2f(h));
            }
        }
        #pragma unroll
        for (int nt = 0; nt < 2; ++nt) {
            s16x8 Bh, Bl;
            #pragma unroll
            for (int e = 0; e < 8; ++e) {
                float x = wvv[nt][e];
                short h = f2bf(x);
                Bh[e] = h;
                Bl[e] = f2bf(x - bf2f(h));
            }
            #pragma unroll
            for (int mt = 0; mt < 4; ++mt) {
                acc[mt][nt] = __builtin_amdgcn_mfma_f32_16x16x32_bf16(Ah[mt], Bh, acc[mt][nt], 0, 0, 0);
                acc[mt][nt] = __builtin_amdgcn_mfma_f32_16x16x32_bf16(Al[mt], Bh, acc[mt][nt], 0, 0, 0);
                acc[mt][nt] = __builtin_amdgcn_mfma_f32_16x16x32_bf16(Ah[mt], Bl, acc[mt][nt], 0, 0, 0);
            }
        }
    }
    #pragma unroll
    for (int mt = 0; mt < 4; ++mt)
        #pragma unroll
        for (int nt = 0; nt < 2; ++nt) {
            const int c = c0 + nt * 16 + cin;
            #pragma unroll
            for (int r = 0; r < 4; ++r)
                outp[(mt * 16 + q * 4 + r) * 512 + c] = acc[mt][nt][r];
        }
}

__global__ __launch_bounds__(256)
void caps_squash_inplace(float* __restrict__ out)
{
    const int o = blockIdx.x * 256 + threadIdx.x;
    float s = out[o];
    float s2 = s * s;
    s2 += __shfl_xor(s2, 1);
    s2 += __shfl_xor(s2, 2);
    s2 += __shfl_xor(s2, 4);
    s2 += __shfl_xor(s2, 8);
    const float scale = s2 / (1.0f + s2);
    out[o] = s * scale / sqrtf(s2 + 1e-7f);
}
// ----------------------------------------------------------------------

extern "C" void kernel_launch(void* const* d_in, const int* in_sizes, int n_in,
                              void* d_out, int out_size, void* d_ws, size_t ws_size,
                              hipStream_t stream)
{
    (void)in_sizes; (void)n_in; (void)out_size;
    const float* In = (const float*)d_in[0];   // [64][2048][8]
    const float* W  = (const float*)d_in[1];   // [2048][32][8][16]
    float* out = (float*)d_out;                // 32768 floats
    float* ws  = (float*)d_ws;

    const size_t need = 32768u * sizeof(float) + (2u << 20) * sizeof(short) * 2; // 4.25 MB
    if (ws_size >= need) {
        caps_prep    <<<dim3(1024),     dim3(256), 0, stream>>>(In, ws);
        caps_gemm_at <<<dim3(64, 8),    dim3(256), 0, stream>>>(W, ws);
        caps_squash  <<<dim3(128),      dim3(256), 0, stream>>>(ws, out);
    } else {
        caps_gemm_direct   <<<dim3(1, 4), dim3(256), 0, stream>>>(In, W, out);
        caps_squash_inplace<<<dim3(128),  dim3(256), 0, stream>>>(out);
    }
}

// Round 8
// 93.738 us; speedup vs baseline: 1.0667x; 1.0667x over previous
//
#include <hip/hip_runtime.h>
#include <hip/hip_bf16.h>
#include <stdint.h>

// CapsNet routing, size-1 softmax axis => cj==1 => one GEMM + squash:
//   s[b][c] = sum_t In[b][t] * W2[t][c]   b<64, t<16384 (=i*8+k), c<512 (=j*16+l)
//   W2[t][c] addr in W[I][J][K][L]: i*4096 + j*128 + k*16 + l
// Verified (rounds 3/4/6 PASS) mfma_f32_16x16x32_bf16 layouts:
//   A[row][k]: row=lane&15, k=(lane>>4)*8+e ; B same k mapping, col=lane&15
//   D[row][col]: col=lane&15, row=(lane>>4)*4+reg
// fp32 accuracy via hi/lo bf16 split (hh + lh + hl).
// Round-7/8: best-measured round-3 structure (register pipeline, no LDS,
// no barriers, no atomics, no prep) with partial traffic cut 4x:
// KSPLITS=64 with ONE j per wave -> 8 MB partials instead of 32 MB round-trip.

using f32x4 = __attribute__((ext_vector_type(4))) float;
using s16x8 = __attribute__((ext_vector_type(8))) short;

__device__ __forceinline__ short f2bf(float x) {
    __hip_bfloat16 h = __float2bfloat16(x);   // RNE
    return *reinterpret_cast<short*>(&h);
}
__device__ __forceinline__ float bf2f(short s) {
    return __uint_as_float(((uint32_t)(uint16_t)s) << 16);
}

struct WReg { float v[8];    };   // W2[kb+q*8+e][j*16+cin], k=e
struct IBuf { f32x4 v[4][2]; };   // In[mt*16+cin][kb+q*8 ..+7]

__global__ __launch_bounds__(256)
void caps_gemm(const float* __restrict__ In, const float* __restrict__ W,
               float* __restrict__ ws)
{
    const int tid  = threadIdx.x;
    const int wv   = tid >> 6;
    const int lane = tid & 63;
    const int q    = lane >> 4;
    const int cin  = lane & 15;
    const int kb0  = blockIdx.x * 256;       // 64 k-splits of 256 t
    const int j    = blockIdx.y * 4 + wv;    // wave owns c-range [j*16, j*16+16)

    const float* wbase = W + (size_t)j * 128 + cin;

    f32x4 acc[4] = {};                       // [mt]: D = 16b x 16c

    auto load_step = [&](int s, WReg& wr, IBuf& ib) {
        const int i0 = (kb0 >> 3) + s * 4 + q;          // t-run q*8 is 8-aligned
        const float* wp = wbase + (size_t)i0 * 4096;
        #pragma unroll
        for (int e = 0; e < 8; ++e) wr.v[e] = wp[e * 16];   // 64B lines fully used
        const int kb = kb0 + s * 32 + q * 8;
        #pragma unroll
        for (int mt = 0; mt < 4; ++mt) {
            const float* ip = In + (size_t)(mt * 16 + cin) * 16384 + kb;
            ib.v[mt][0] = *(const f32x4*)(ip);
            ib.v[mt][1] = *(const f32x4*)(ip + 4);
        }
    };

    auto compute = [&](const WReg& wr, const IBuf& ib) {
        s16x8 Bh, Bl;
        #pragma unroll
        for (int e = 0; e < 8; ++e) {
            short h = f2bf(wr.v[e]);
            Bh[e] = h;
            Bl[e] = f2bf(wr.v[e] - bf2f(h));
        }
        #pragma unroll
        for (int mt = 0; mt < 4; ++mt) {
            s16x8 Ah, Al;
            #pragma unroll
            for (int e = 0; e < 8; ++e) {
                float x = ib.v[mt][e >> 2][e & 3];
                short h = f2bf(x);
                Ah[e] = h;
                Al[e] = f2bf(x - bf2f(h));
            }
            acc[mt] = __builtin_amdgcn_mfma_f32_16x16x32_bf16(Ah, Bh, acc[mt], 0, 0, 0);
            acc[mt] = __builtin_amdgcn_mfma_f32_16x16x32_bf16(Al, Bh, acc[mt], 0, 0, 0);
            acc[mt] = __builtin_amdgcn_mfma_f32_16x16x32_bf16(Ah, Bl, acc[mt], 0, 0, 0);
        }
    };

    WReg wA, wB; IBuf iA, iB;                // statically-named double buffer
    load_step(0, wA, iA);
    #pragma unroll 1
    for (int ss = 0; ss < 8; ss += 2) {
        load_step(ss + 1, wB, iB);
        compute(wA, iA);
        if (ss + 2 < 8) load_step(ss + 2, wA, iA);
        compute(wB, iB);
    }

    // D: row b = mt*16 + q*4 + r, col c = j*16 + cin ; slab per k-split
    float* wsb = ws + (size_t)blockIdx.x * 32768;
    #pragma unroll
    for (int mt = 0; mt < 4; ++mt) {
        const int b = mt * 16 + q * 4;
        #pragma unroll
        for (int r = 0; r < 4; ++r)
            wsb[(b + r) * 512 + j * 16 + cin] = acc[mt][r];
    }
}

__global__ __launch_bounds__(256)
void caps_finish(const float* __restrict__ ws, float* __restrict__ out)
{
    const int o = blockIdx.x * 256 + threadIdx.x;   // o = b*512 + j*16 + l
    float a[8] = {};
    #pragma unroll 1
    for (int ks = 0; ks < 64; ks += 8)              // ILP-8 chains
        #pragma unroll
        for (int u = 0; u < 8; ++u)
            a[u] += ws[(size_t)(ks + u) * 32768 + o];
    float s = ((a[0] + a[1]) + (a[2] + a[3])) + ((a[4] + a[5]) + (a[6] + a[7]));
    float s2 = s * s;                               // sum over l (16 lanes)
    s2 += __shfl_xor(s2, 1);
    s2 += __shfl_xor(s2, 2);
    s2 += __shfl_xor(s2, 4);
    s2 += __shfl_xor(s2, 8);
    const float scale = s2 / (1.0f + s2);
    out[o] = s * scale / sqrtf(s2 + 1e-7f);
}

// ---------- fallback (ws too small; practically never taken) ----------
__global__ __launch_bounds__(256)
void caps_gemm_direct(const float* __restrict__ In, const float* __restrict__ W,
                      float* __restrict__ outp)
{
    const int tid = threadIdx.x, wv = tid >> 6, lane = tid & 63;
    const int q = lane >> 4, cin = lane & 15;
    const int c0 = blockIdx.y * 128 + wv * 32;
    f32x4 acc[4][2] = {};
    #pragma unroll 1
    for (int ssk = 0; ssk < 512; ++ssk) {
        const int kb = ssk * 32;
        const int i0 = (kb >> 3) + q;
        float wvv[2][8];
        s16x8 Ah[4], Al[4];
        #pragma unroll
        for (int nt = 0; nt < 2; ++nt) {
            const int c = c0 + nt * 16 + cin;
            const float* wp = W + (size_t)i0 * 4096 + (c >> 4) * 128 + (c & 15);
            #pragma unroll
            for (int e = 0; e < 8; ++e) wvv[nt][e] = wp[e * 16];
        }
        #pragma unroll
        for (int mt = 0; mt < 4; ++mt) {
            const float* ip = In + (size_t)(mt * 16 + cin) * 16384 + kb + q * 8;
            #pragma unroll
            for (int e = 0; e < 8; ++e) {
                float x = ip[e];
                short h = f2bf(x);
                Ah[mt][e] = h;
                Al[mt][e] = f2bf(x - bf2f(h));
            }
        }
        #pragma unroll
        for (int nt = 0; nt < 2; ++nt) {
            s16x8 Bh, Bl;
            #pragma unroll
            for (int e = 0; e < 8; ++e) {
                float x = wvv[nt][e];
                short h = f2bf(x);
                Bh[e] = h;
                Bl[e] = f2bf(x - bf2f(h));
            }
            #pragma unroll
            for (int mt = 0; mt < 4; ++mt) {
                acc[mt][nt] = __builtin_amdgcn_mfma_f32_16x16x32_bf16(Ah[mt], Bh, acc[mt][nt], 0, 0, 0);
                acc[mt][nt] = __builtin_amdgcn_mfma_f32_16x16x32_bf16(Al[mt], Bh, acc[mt][nt], 0, 0, 0);
                acc[mt][nt] = __builtin_amdgcn_mfma_f32_16x16x32_bf16(Ah[mt], Bl, acc[mt][nt], 0, 0, 0);
            }
        }
    }
    #pragma unroll
    for (int mt = 0; mt < 4; ++mt)
        #pragma unroll
        for (int nt = 0; nt < 2; ++nt) {
            const int c = c0 + nt * 16 + cin;
            #pragma unroll
            for (int r = 0; r < 4; ++r)
                outp[(mt * 16 + q * 4 + r) * 512 + c] = acc[mt][nt][r];
        }
}

__global__ __launch_bounds__(256)
void caps_squash_inplace(float* __restrict__ out)
{
    const int o = blockIdx.x * 256 + threadIdx.x;
    float s = out[o];
    float s2 = s * s;
    s2 += __shfl_xor(s2, 1);
    s2 += __shfl_xor(s2, 2);
    s2 += __shfl_xor(s2, 4);
    s2 += __shfl_xor(s2, 8);
    const float scale = s2 / (1.0f + s2);
    out[o] = s * scale / sqrtf(s2 + 1e-7f);
}
// ----------------------------------------------------------------------

extern "C" void kernel_launch(void* const* d_in, const int* in_sizes, int n_in,
                              void* d_out, int out_size, void* d_ws, size_t ws_size,
                              hipStream_t stream)
{
    (void)in_sizes; (void)n_in; (void)out_size;
    const float* In = (const float*)d_in[0];   // [64][2048][8]
    const float* W  = (const float*)d_in[1];   // [2048][32][8][16]
    float* out = (float*)d_out;                // 32768 floats
    float* ws  = (float*)d_ws;

    const size_t need = 64u * 32768u * sizeof(float);   // 8 MiB of partials
    if (ws_size >= need) {
        caps_gemm  <<<dim3(64, 8), dim3(256), 0, stream>>>(In, W, ws);
        caps_finish<<<dim3(128),   dim3(256), 0, stream>>>(ws, out);
    } else {
        caps_gemm_direct   <<<dim3(1, 4), dim3(256), 0, stream>>>(In, W, out);
        caps_squash_inplace<<<dim3(128),  dim3(256), 0, stream>>>(out);
    }
}